// Round 11
// baseline (368.852 us; speedup 1.0000x reference)
//
#include <hip/hip_runtime.h>
#include <hip/hip_bf16.h>
#include <hip/hip_fp16.h>
#include <stdint.h>
#include <math.h>

#define TSEQ 768
#define TOUT 384
#define DM   512
#define NH   8
#define DKH  64

typedef short bf16x8 __attribute__((ext_vector_type(8)));
typedef float f32x4  __attribute__((ext_vector_type(4)));
typedef __fp16 f16x2 __attribute__((ext_vector_type(2)));   // matches cvt_pkrtz return type

__device__ __forceinline__ unsigned short f2bf(float f){
  unsigned int u = __float_as_uint(f);
  unsigned int r = (u + 0x7FFFu + ((u >> 16) & 1u)) >> 16;
  return (unsigned short)r;
}

#define MFMA(a,b,c) __builtin_amdgcn_mfma_f32_16x16x32_bf16((a),(b),(c),0,0,0)

// async global->LDS, 16B per lane. LDS dest = wave-uniform base + lane*16.
typedef __attribute__((address_space(1))) const void* gas_ptr;
typedef __attribute__((address_space(3))) void*       las_ptr;
__device__ __forceinline__ void gload16(const void* g, void* l){
  __builtin_amdgcn_global_load_lds((gas_ptr)g, (las_ptr)l, 16, 0, 0);
}

// Cross-lane xor-exchange on a packed u32, dl compile-time.
// dl=1: quad_perm [1,0,3,2]. dl=2: quad_perm [2,3,0,1]. dl=8: row_ror:8 (==xor8).
// dl=4: ds_swizzle BitMode xor4 (0x101F). dl=16/32: __shfl_xor (ds_bpermute).
// All five proven bit-exact in r5.
__device__ __forceinline__ unsigned xlane_xor_u(unsigned x, int dl){
  int xi = (int)x;
  if (dl == 1)      return (unsigned)__builtin_amdgcn_update_dpp(xi, xi, 0xB1, 0xF, 0xF, true);
  else if (dl == 2) return (unsigned)__builtin_amdgcn_update_dpp(xi, xi, 0x4E, 0xF, 0xF, true);
  else if (dl == 4) return (unsigned)__builtin_amdgcn_ds_swizzle(xi, 0x101F);
  else if (dl == 8) return (unsigned)__builtin_amdgcn_update_dpp(xi, xi, 0x128, 0xF, 0xF, true);
  else return (unsigned)__shfl_xor(xi, dl, 64);
}
__device__ __forceinline__ float xlane_xor_f(float x, int dl){
  return __int_as_float((int)xlane_xor_u((unsigned)__float_as_int(x), dl));
}

// packed f16x2 min/max -> v_pk_max_f16 / v_pk_min_f16 via elementwise builtins
__device__ __forceinline__ unsigned pmax2(unsigned a, unsigned b){
  f16x2 r = __builtin_elementwise_max(*reinterpret_cast<f16x2*>(&a),
                                      *reinterpret_cast<f16x2*>(&b));
  return *reinterpret_cast<unsigned*>(&r);
}
__device__ __forceinline__ unsigned pmin2(unsigned a, unsigned b){
  f16x2 r = __builtin_elementwise_min(*reinterpret_cast<f16x2*>(&a),
                                      *reinterpret_cast<f16x2*>(&b));
  return *reinterpret_cast<unsigned*>(&r);
}
__device__ __forceinline__ unsigned pkrtz(float a, float b){
  f16x2 h = __builtin_amdgcn_cvt_pkrtz(a, b);   // lo=a, hi=b
  return *reinterpret_cast<unsigned*>(&h);
}
__device__ __forceinline__ float lo16f(unsigned u){
  f16x2 h = *reinterpret_cast<f16x2*>(&u); return (float)h[0];
}
__device__ __forceinline__ float hi16f(unsigned u){
  f16x2 h = *reinterpret_cast<f16x2*>(&u); return (float)h[1];
}

__device__ __forceinline__ void cvt8(const float* __restrict__ in,
                                     unsigned short* __restrict__ out){
  float4 a = *reinterpret_cast<const float4*>(in);
  float4 b = *reinterpret_cast<const float4*>(in + 4);
  unsigned short u[8] = {f2bf(a.x),f2bf(a.y),f2bf(a.z),f2bf(a.w),
                         f2bf(b.x),f2bf(b.y),f2bf(b.z),f2bf(b.w)};
  *reinterpret_cast<bf16x8*>(out) = *reinterpret_cast<bf16x8*>(u);
}

// ---------------- K0: all fp32->bf16 conversions in one launch ----------------
// blocks [0,3072): x (6291456 elems); [3072,3456): Wqkv (786432);
// [3456,4480): Wconv repack [co][ci][3] -> [j][co][ci] (262144 idx).
__global__ __launch_bounds__(256) void k_cvt_all(const float* __restrict__ x,
    const float* __restrict__ wq, const float* __restrict__ wconv,
    unsigned short* __restrict__ xb, unsigned short* __restrict__ wqb,
    unsigned short* __restrict__ wc3){
  int bid = blockIdx.x;
  if (bid < 3072){
    int i = (bid*256 + threadIdx.x)*8;
    cvt8(x + i, xb + i);
  } else if (bid < 3456){
    int i = ((bid-3072)*256 + threadIdx.x)*8;
    cvt8(wq + i, wqb + i);
  } else {
    int idx = (bid-3456)*256 + threadIdx.x;
    float w0 = wconv[idx*3+0], w1 = wconv[idx*3+1], w2 = wconv[idx*3+2];
    wc3[idx]          = f2bf(w0);
    wc3[262144 + idx] = f2bf(w1);
    wc3[524288 + idx] = f2bf(w2);
  }
}

// ---------------- K1: QKV projection GEMM, m97-style 128x128 tile ----------------
__global__ __launch_bounds__(256) void k_qkv(const unsigned short* __restrict__ xb,
    const unsigned short* __restrict__ wq, const float* __restrict__ bias,
    unsigned short* __restrict__ qe, unsigned short* __restrict__ kb,
    unsigned short* __restrict__ vb){
  __shared__ unsigned short sA[128*32];
  __shared__ unsigned short sB[128*32];
  int bm = blockIdx.x % 96, bn = blockIdx.x / 96;
  int m0 = bm*128, n0 = bn*128;
  int tid = threadIdx.x, w = tid>>6, l = tid&63;
  int wr = w>>1, wc = w&1, lr = l&15, lk = (l>>4)*8;

  int srow = w*32 + (l>>2);
  int scol = (l&3)*8;
  const unsigned short* gA = xb + (size_t)(m0 + srow)*DM + scol;
  const unsigned short* gB = wq + (size_t)(n0 + srow)*DM + scol;
  unsigned short* dA = sA + w*1024;
  unsigned short* dB = sB + w*1024;

  const unsigned short* ra = sA + (wr*64 + lr)*32 + lk;
  const unsigned short* rb = sB + (wc*64 + lr)*32 + lk;

  f32x4 z = {0.f,0.f,0.f,0.f};
  f32x4 acc[4][4] = {{z,z,z,z},{z,z,z,z},{z,z,z,z},{z,z,z,z}};

  #pragma unroll 1
  for (int ks=0; ks<16; ++ks){
    int k0 = ks*32;
    gload16(gA + k0,          dA);
    gload16(gA + 16*DM + k0,  dA + 512);
    gload16(gB + k0,          dB);
    gload16(gB + 16*DM + k0,  dB + 512);
    __syncthreads();
    bf16x8 af[4], bfr[4];
    #pragma unroll
    for (int f=0; f<4; ++f){
      af[f]  = *reinterpret_cast<const bf16x8*>(ra + f*512);
      bfr[f] = *reinterpret_cast<const bf16x8*>(rb + f*512);
    }
    #pragma unroll
    for (int fq=0; fq<4; ++fq)
      #pragma unroll
      for (int fn=0; fn<4; ++fn)
        acc[fq][fn] = MFMA(af[fq], bfr[fn], acc[fq][fn]);
    __syncthreads();
  }

  int region = n0 >> 9;
  #pragma unroll
  for (int fq=0; fq<4; ++fq)
    #pragma unroll
    for (int fn=0; fn<4; ++fn)
      #pragma unroll
      for (int r=0; r<4; ++r){
        int m = m0 + wr*64 + fq*16 + (l>>4)*4 + r;
        int b = m / TSEQ, t = m - b*TSEQ;
        int n = n0 + wc*64 + fn*16 + lr;
        float val = acc[fq][fn][r] + bias[n];
        unsigned short bv = f2bf(val);
        int bh = b*NH + ((n>>6)&7); int d = n & 63;
        if (region == 0){ if((t&1)==0) qe[((size_t)bh*TOUT + (t>>1))*DKH + d] = bv; }
        else if (region == 1){ kb[((size_t)bh*TSEQ + t)*DKH + d] = bv; }
        else { vb[((size_t)bh*TSEQ + t)*DKH + d] = bv; }
      }
}

// ---------------- K1b: v transpose [bh][768][64] -> [bh][64][768] ----------------
__global__ __launch_bounds__(256) void k_vt(const unsigned short* __restrict__ vb,
                                            unsigned short* __restrict__ vT){
  __shared__ unsigned short tile[64][72];
  int bh = blockIdx.x / 12, tt = blockIdx.x % 12;
  int t0 = tt*64;
  int tid = threadIdx.x;
  int r = tid >> 2, c0 = (tid & 3) * 16;
  const unsigned short* src = vb + ((size_t)bh*TSEQ + t0 + r)*DKH + c0;
  *reinterpret_cast<bf16x8*>(&tile[r][c0])   = *reinterpret_cast<const bf16x8*>(src);
  *reinterpret_cast<bf16x8*>(&tile[r][c0+8]) = *reinterpret_cast<const bf16x8*>(src + 8);
  __syncthreads();
  int d = r;
  unsigned short tmp[16];
  #pragma unroll
  for (int j=0;j<16;++j) tmp[j] = tile[c0+j][d];
  unsigned short* dst = vT + ((size_t)bh*DKH + d)*TSEQ + t0 + c0;
  *reinterpret_cast<bf16x8*>(dst)     = *reinterpret_cast<bf16x8*>(tmp);
  *reinterpret_cast<bf16x8*>(dst + 8) = *reinterpret_cast<bf16x8*>(tmp + 8);
}

// ---------------- K2: scores MFMA + 2-row-packed f16 bitonic sort + softmax + PV MFMA ----------------
// Sort uses stage-level sign-flip normalization: within stage k (>=16), lanes whose
// elements sort ascending get sign-negated (xor 0x80008000, bit-exact involution),
// making every comparator "max to lower index" — in-lane phases become static
// (no cndmask), cross-lane select reduces to (l & dl)==0. Output bit-identical.
#define SQ_ROWB 3088   // bytes per fp32 score row (772 floats, 16B aligned)
__global__ __launch_bounds__(512, 4) void k_attn(const unsigned short* __restrict__ qe,
    const unsigned short* __restrict__ kb, const unsigned short* __restrict__ vT,
    float* __restrict__ attn){
  __shared__ alignas(16) char sq_raw[16*SQ_ROWB];   // 49408 B
  int bh = blockIdx.x / 24, qb = blockIdx.x % 24;
  int tid = threadIdx.x, w = tid>>6, l = tid&63, lr = l&15, lk = (l>>4)*8;

  // ---- phase A: scores C[16 q][768 k] = q[16][64] . kb[768][64]^T, scaled 1/8
  const unsigned short* qbase = qe + ((size_t)bh*TOUT + qb*16)*DKH;
  bf16x8 qa0 = *reinterpret_cast<const bf16x8*>(qbase + lr*DKH + lk);
  bf16x8 qa1 = *reinterpret_cast<const bf16x8*>(qbase + lr*DKH + 32 + lk);
  const unsigned short* kbase = kb + (size_t)bh*TSEQ*DKH;
  #pragma unroll
  for (int i=0;i<6;++i){
    int nt = w + 8*i;
    const unsigned short* kr = kbase + (size_t)(nt*16 + lr)*DKH + lk;
    bf16x8 B0 = *reinterpret_cast<const bf16x8*>(kr);
    bf16x8 B1 = *reinterpret_cast<const bf16x8*>(kr + 32);
    f32x4 c = {0.f,0.f,0.f,0.f};
    c = MFMA(qa0,B0,c);
    c = MFMA(qa1,B1,c);
    int col = nt*16 + lr;
    int A = col*4;
    int sw = A ^ (((A >> 8) & 7) << 4);   // XOR swizzle within row (16B slots)
    #pragma unroll
    for (int r=0;r<4;++r){
      int qr = (l>>4)*4 + r;
      *reinterpret_cast<float*>(sq_raw + qr*SQ_ROWB + sw) = c[r] * 0.125f;
    }
  }
  __syncthreads();

  // ---- phase B: one packed network pass sorts both of this wave's rows
  {
    char* rowA = sq_raw + (w*2)*SQ_ROWB;
    char* rowB = rowA + SQ_ROWB;
    unsigned wv[16];
    if (l < 48){
      #pragma unroll
      for (int i4=0;i4<4;++i4){
        int A = l*64 + i4*16;
        int Asw = A ^ (((A >> 8) & 7) << 4);
        f32x4 va = *reinterpret_cast<f32x4*>(rowA + Asw);
        f32x4 vb = *reinterpret_cast<f32x4*>(rowB + Asw);
        wv[i4*4+0] = pkrtz(va[0], vb[0]);
        wv[i4*4+1] = pkrtz(va[1], vb[1]);
        wv[i4*4+2] = pkrtz(va[2], vb[2]);
        wv[i4*4+3] = pkrtz(va[3], vb[3]);
      }
    } else {
      #pragma unroll
      for (int j=0;j<16;++j) wv[j] = 0xFC00FC00u;   // (-inf, -inf) f16
    }
    #pragma unroll
    for (int k = 2; k <= 1024; k <<= 1){
      if (k >= 16){
        bool up = (k == 16) ? ((l & 1) == 0) : ((l & (k >> 4)) == 0);
        unsigned negmask = up ? 0u : 0x80008000u;
        #pragma unroll
        for (int j=0;j<16;++j) wv[j] ^= negmask;
        // cross-lane phases (k>=32): keep max where (l & dl)==0
        #pragma unroll
        for (int D = k>>1; D >= 16; D >>= 1){
          int dl = D >> 4;
          bool sel = (l & dl) == 0;
          #pragma unroll
          for (int j=0;j<16;++j){
            unsigned y  = xlane_xor_u(wv[j], dl);
            unsigned mx = pmax2(wv[j], y), mn = pmin2(wv[j], y);
            wv[j] = sel ? mx : mn;
          }
        }
        // in-lane phases: static, max to lower j
        #pragma unroll
        for (int D = 8; D >= 1; D >>= 1){
          #pragma unroll
          for (int j=0;j<16;++j){
            if ((j & D) == 0){
              int j2 = j | D;
              unsigned mx = pmax2(wv[j], wv[j2]), mn = pmin2(wv[j], wv[j2]);
              wv[j] = mx; wv[j2] = mn;
            }
          }
        }
        #pragma unroll
        for (int j=0;j<16;++j) wv[j] ^= negmask;
      } else {
        // k = 2,4,8: in-lane only, static direction by (j & k)
        #pragma unroll
        for (int D = k>>1; D >= 1; D >>= 1){
          #pragma unroll
          for (int j=0;j<16;++j){
            if ((j & D) == 0){
              int j2 = j | D;
              unsigned mx = pmax2(wv[j], wv[j2]), mn = pmin2(wv[j], wv[j2]);
              if ((j & k) == 0){ wv[j] = mx; wv[j2] = mn; }
              else             { wv[j] = mn; wv[j2] = mx; }
            }
          }
        }
      }
    }
    // softmax per row (lo = row A, hi = row B)
    #pragma unroll 1
    for (int half=0; half<2; ++half){
      float xf[16];
      #pragma unroll
      for (int j=0;j<16;++j) xf[j] = half ? hi16f(wv[j]) : lo16f(wv[j]);
      float mx0 = __shfl(xf[0], 0, 64);
      float s = 0.f;
      #pragma unroll
      for (int j=0;j<16;++j){ xf[j] = __expf(xf[j]-mx0); s += xf[j]; }
      #pragma unroll
      for (int o=1;o<64;o<<=1) s += xlane_xor_f(s, o);
      float inv = 1.f / s;
      if (l < 48){
        unsigned short u[16];
        #pragma unroll
        for (int j=0;j<16;++j) u[j] = f2bf(xf[j]*inv);
        char* pp = (half ? rowB : rowA) + l*32;
        *reinterpret_cast<bf16x8*>(pp)      = *reinterpret_cast<bf16x8*>(u);
        *reinterpret_cast<bf16x8*>(pp + 16) = *reinterpret_cast<bf16x8*>(u + 8);
      }
    }
  }
  __syncthreads();

  // ---- phase C: PV. C[16 q][64 d] = P[16][768] . vT[64][768]^T. waves 0-3 only.
  if (w < 4){
    f32x4 o = {0.f,0.f,0.f,0.f};
    const unsigned short* vtb = vT + ((size_t)bh*DKH + w*16 + lr)*TSEQ + lk;
    const char* prow = sq_raw + lr*SQ_ROWB + (l>>4)*16;
    #pragma unroll
    for (int ks=0; ks<24; ++ks){
      bf16x8 a  = *reinterpret_cast<const bf16x8*>(prow + ks*64);
      bf16x8 bb = *reinterpret_cast<const bf16x8*>(vtb + ks*32);
      o = MFMA(a,bb,o);
    }
    int b = bh >> 3, h = bh & 7;
    float* ab = attn + ((size_t)b*TOUT + qb*16)*DM + h*DKH + w*16 + lr;
    #pragma unroll
    for (int r=0;r<4;++r){
      int qr = (l>>4)*4 + r;
      ab[(size_t)qr*DM] = o[r];
    }
  }
}

// ---------------- K3: conv as 3 accumulated GEMMs, m97-style 128x64 tile ----------------
// 384 blocks (48 x 8) for better CU coverage. Same (j outer, ks inner, 32-chunk)
// accumulation order => bit-identical accumulators. Left-pad handled by clamped
// source row + zeroing LDS A row 0 between barriers.
__global__ __launch_bounds__(256) void k_conv(const unsigned short* __restrict__ xb,
    const unsigned short* __restrict__ wc, const float* __restrict__ bconv,
    float* __restrict__ res){
  __shared__ unsigned short sA[128*32];
  __shared__ unsigned short sB[64*32];
  int bm = blockIdx.x % 48, bn = blockIdx.x / 48;   // 48 x 8 blocks
  int m0 = bm*128, n0 = bn*64;
  int tid = threadIdx.x, w = tid>>6, l = tid&63;
  int wr = w>>1, wc2 = w&1, lr = l&15, lk = (l>>4)*8;
  int b = m0 / TOUT, t0 = m0 - b*TOUT;   // 384 = 3*128: tile never straddles batches

  int srowA = w*32 + (l>>2);       // A rows, 2 issues (second = +16)
  int srowB = w*16 + (l>>2);       // B rows, 1 issue
  int scol = (l&3)*8;
  const unsigned short* xrow = xb + (size_t)b*TSEQ*DM;
  unsigned short* dA = sA + w*1024;
  unsigned short* dB = sB + w*512;
  const unsigned short* ra  = sA + (wr*64 + lr)*32 + lk;
  const unsigned short* rb_ = sB + (wc2*32 + lr)*32 + lk;

  f32x4 z = {0.f,0.f,0.f,0.f};
  f32x4 acc[4][2] = {{z,z},{z,z},{z,z},{z,z}};
  bool zfix = (t0 == 0);

  #pragma unroll 1
  for (int j=0; j<3; ++j){
    int tin0 = 2*(t0 + srowA) + j - 1;
    int tin0c = tin0 < 0 ? 0 : tin0;
    const unsigned short* gA0 = xrow + (size_t)tin0c*DM + scol;
    const unsigned short* gA1 = xrow + (size_t)(tin0 + 32)*DM + scol;
    const unsigned short* gB  = wc + (size_t)j*262144 + (size_t)(n0 + srowB)*DM + scol;
    bool dz = zfix && (j == 0);
    #pragma unroll 1
    for (int ks=0; ks<16; ++ks){
      int k0 = ks*32;
      gload16(gA0 + k0, dA);
      gload16(gA1 + k0, dA + 512);
      gload16(gB + k0,  dB);
      __syncthreads();
      if (dz && tid < 4){
        bf16x8 zz = {0,0,0,0,0,0,0,0};
        *reinterpret_cast<bf16x8*>(sA + tid*8) = zz;   // zero A row 0 (pad)
      }
      __syncthreads();
      bf16x8 af[4], bfr[2];
      #pragma unroll
      for (int f=0; f<4; ++f) af[f] = *reinterpret_cast<const bf16x8*>(ra + f*512);
      #pragma unroll
      for (int f=0; f<2; ++f) bfr[f] = *reinterpret_cast<const bf16x8*>(rb_ + f*512);
      #pragma unroll
      for (int fq=0; fq<4; ++fq)
        #pragma unroll
        for (int fn=0; fn<2; ++fn)
          acc[fq][fn] = MFMA(af[fq], bfr[fn], acc[fq][fn]);
      __syncthreads();
    }
  }

  #pragma unroll
  for (int fq=0; fq<4; ++fq)
    #pragma unroll
    for (int fn=0; fn<2; ++fn)
      #pragma unroll
      for (int r=0; r<4; ++r){
        int t = t0 + wr*64 + fq*16 + (l>>4)*4 + r;
        int n = n0 + wc2*32 + fn*16 + lr;
        size_t idx = ((size_t)b*TOUT + t)*DM + n;
        res[idx] = acc[fq][fn][r] + bconv[n] + res[idx];
      }
}

// ---------------- K4: LayerNorm over D=512, one wave per row ----------------
__global__ __launch_bounds__(256) void k_ln(const float* __restrict__ res,
    const float* __restrict__ gamma, const float* __restrict__ beta,
    float* __restrict__ out){
  int row = blockIdx.x*4 + (threadIdx.x>>6);
  int l = threadIdx.x & 63;
  const float* rp = res + (size_t)row*DM + l*8;
  float4 v0 = *reinterpret_cast<const float4*>(rp);
  float4 v1 = *reinterpret_cast<const float4*>(rp + 4);
  float s = v0.x+v0.y+v0.z+v0.w + v1.x+v1.y+v1.z+v1.w;
  #pragma unroll
  for (int o=1;o<64;o<<=1) s += __shfl_xor(s, o, 64);
  float mean = s * (1.f/512.f);
  float d0=v0.x-mean, d1=v0.y-mean, d2=v0.z-mean, d3=v0.w-mean;
  float d4=v1.x-mean, d5=v1.y-mean, d6=v1.z-mean, d7=v1.w-mean;
  float q = d0*d0+d1*d1+d2*d2+d3*d3+d4*d4+d5*d5+d6*d6+d7*d7;
  #pragma unroll
  for (int o=1;o<64;o<<=1) q += __shfl_xor(q, o, 64);
  float var = q * (1.f/512.f);
  float inv = rsqrtf(var + 1e-5f);
  float4 g0 = *reinterpret_cast<const float4*>(gamma + l*8);
  float4 g1 = *reinterpret_cast<const float4*>(gamma + l*8 + 4);
  float4 b0 = *reinterpret_cast<const float4*>(beta + l*8);
  float4 b1 = *reinterpret_cast<const float4*>(beta + l*8 + 4);
  float4 o0, o1;
  o0.x = d0*inv*g0.x + b0.x; o0.y = d1*inv*g0.y + b0.y;
  o0.z = d2*inv*g0.z + b0.z; o0.w = d3*inv*g0.w + b0.w;
  o1.x = d4*inv*g1.x + b1.x; o1.y = d5*inv*g1.y + b1.y;
  o1.z = d6*inv*g1.z + b1.z; o1.w = d7*inv*g1.w + b1.w;
  float* op = out + (size_t)row*DM + l*8;
  *reinterpret_cast<float4*>(op)     = o0;
  *reinterpret_cast<float4*>(op + 4) = o1;
}

extern "C" void kernel_launch(void* const* d_in, const int* in_sizes, int n_in,
                              void* d_out, int out_size, void* d_ws, size_t ws_size,
                              hipStream_t stream){
  const float* x     = (const float*)d_in[0];
  const float* Wqkv  = (const float*)d_in[1];
  const float* bqkv  = (const float*)d_in[2];
  const float* Wconv = (const float*)d_in[3];
  const float* bconv = (const float*)d_in[4];
  const float* gamma = (const float*)d_in[5];
  const float* beta  = (const float*)d_in[6];
  float* out = (float*)d_out;

  char* ws = (char*)d_ws;
  size_t off = 0;
  auto alloc = [&](size_t bytes)->char*{
    char* p = ws + off; off += (bytes + 255) & ~(size_t)255; return p;
  };
  unsigned short* xb  = (unsigned short*)alloc(6291456ull*2);  // x bf16 [12288][512]
  unsigned short* wqb = (unsigned short*)alloc(786432ull*2);   // Wqkv bf16 [1536][512]
  unsigned short* wc3 = (unsigned short*)alloc(786432ull*2);   // Wconv repack [3][512][512]
  unsigned short* qeb = (unsigned short*)alloc(3145728ull*2);  // q even rows [128][384][64]
  unsigned short* kbb = (unsigned short*)alloc(6291456ull*2);  // k [128][768][64]
  unsigned short* vbb = (unsigned short*)alloc(6291456ull*2);  // v [128][768][64]
  unsigned short* vtb = (unsigned short*)alloc(6291456ull*2);  // v^T [128][64][768]
  float*          resb = (float*)alloc(3145728ull*4);          // attn(even) then +conv residual

  k_cvt_all<<<dim3(4480), dim3(256), 0, stream>>>(x, Wqkv, Wconv, xb, wqb, wc3);
  k_qkv<<<dim3(1152), dim3(256), 0, stream>>>(xb, wqb, bqkv, qeb, kbb, vbb);
  k_vt<<<dim3(1536), dim3(256), 0, stream>>>(vbb, vtb);
  k_attn<<<dim3(3072), dim3(512), 0, stream>>>(qeb, kbb, vtb, resb);
  k_conv<<<dim3(384), dim3(256), 0, stream>>>(xb, wc3, bconv, resb);
  k_ln<<<dim3(1536), dim3(256), 0, stream>>>(resb, gamma, beta, out);
}

// Round 12
// 239.317 us; speedup vs baseline: 1.5413x; 1.5413x over previous
//
#include <hip/hip_runtime.h>
#include <hip/hip_bf16.h>
#include <hip/hip_fp16.h>
#include <stdint.h>
#include <math.h>

#define TSEQ 768
#define TOUT 384
#define DM   512
#define NH   8
#define DKH  64

typedef short bf16x8 __attribute__((ext_vector_type(8)));
typedef float f32x4  __attribute__((ext_vector_type(4)));
typedef __fp16 f16x2 __attribute__((ext_vector_type(2)));   // matches cvt_pkrtz return type

__device__ __forceinline__ unsigned short f2bf(float f){
  unsigned int u = __float_as_uint(f);
  unsigned int r = (u + 0x7FFFu + ((u >> 16) & 1u)) >> 16;
  return (unsigned short)r;
}

#define MFMA(a,b,c) __builtin_amdgcn_mfma_f32_16x16x32_bf16((a),(b),(c),0,0,0)

// async global->LDS, 16B per lane. LDS dest = wave-uniform base + lane*16.
typedef __attribute__((address_space(1))) const void* gas_ptr;
typedef __attribute__((address_space(3))) void*       las_ptr;
__device__ __forceinline__ void gload16(const void* g, void* l){
  __builtin_amdgcn_global_load_lds((gas_ptr)g, (las_ptr)l, 16, 0, 0);
}

// Cross-lane xor-exchange on a packed u32, dl compile-time.
// dl=1: quad_perm [1,0,3,2]. dl=2: quad_perm [2,3,0,1]. dl=8: row_ror:8 (==xor8).
// dl=4: ds_swizzle BitMode xor4 (0x101F). dl=16/32: __shfl_xor (ds_bpermute).
// All five proven bit-exact in r5. NOTE (r11 lesson): these are only fast when
// dl folds to a compile-time constant — keep the calling loop fully unrollable.
__device__ __forceinline__ unsigned xlane_xor_u(unsigned x, int dl){
  int xi = (int)x;
  if (dl == 1)      return (unsigned)__builtin_amdgcn_update_dpp(xi, xi, 0xB1, 0xF, 0xF, true);
  else if (dl == 2) return (unsigned)__builtin_amdgcn_update_dpp(xi, xi, 0x4E, 0xF, 0xF, true);
  else if (dl == 4) return (unsigned)__builtin_amdgcn_ds_swizzle(xi, 0x101F);
  else if (dl == 8) return (unsigned)__builtin_amdgcn_update_dpp(xi, xi, 0x128, 0xF, 0xF, true);
  else return (unsigned)__shfl_xor(xi, dl, 64);
}
__device__ __forceinline__ float xlane_xor_f(float x, int dl){
  return __int_as_float((int)xlane_xor_u((unsigned)__float_as_int(x), dl));
}

// packed f16x2 min/max -> v_pk_max_f16 / v_pk_min_f16 via elementwise builtins
__device__ __forceinline__ unsigned pmax2(unsigned a, unsigned b){
  f16x2 r = __builtin_elementwise_max(*reinterpret_cast<f16x2*>(&a),
                                      *reinterpret_cast<f16x2*>(&b));
  return *reinterpret_cast<unsigned*>(&r);
}
__device__ __forceinline__ unsigned pmin2(unsigned a, unsigned b){
  f16x2 r = __builtin_elementwise_min(*reinterpret_cast<f16x2*>(&a),
                                      *reinterpret_cast<f16x2*>(&b));
  return *reinterpret_cast<unsigned*>(&r);
}
__device__ __forceinline__ unsigned pkrtz(float a, float b){
  f16x2 h = __builtin_amdgcn_cvt_pkrtz(a, b);   // lo=a, hi=b
  return *reinterpret_cast<unsigned*>(&h);
}
__device__ __forceinline__ float lo16f(unsigned u){
  f16x2 h = *reinterpret_cast<f16x2*>(&u); return (float)h[0];
}
__device__ __forceinline__ float hi16f(unsigned u){
  f16x2 h = *reinterpret_cast<f16x2*>(&u); return (float)h[1];
}

__device__ __forceinline__ void cvt8(const float* __restrict__ in,
                                     unsigned short* __restrict__ out){
  float4 a = *reinterpret_cast<const float4*>(in);
  float4 b = *reinterpret_cast<const float4*>(in + 4);
  unsigned short u[8] = {f2bf(a.x),f2bf(a.y),f2bf(a.z),f2bf(a.w),
                         f2bf(b.x),f2bf(b.y),f2bf(b.z),f2bf(b.w)};
  *reinterpret_cast<bf16x8*>(out) = *reinterpret_cast<bf16x8*>(u);
}

// ---------------- K0: all fp32->bf16 conversions in one launch ----------------
__global__ __launch_bounds__(256) void k_cvt_all(const float* __restrict__ x,
    const float* __restrict__ wq, const float* __restrict__ wconv,
    unsigned short* __restrict__ xb, unsigned short* __restrict__ wqb,
    unsigned short* __restrict__ wc3){
  int bid = blockIdx.x;
  if (bid < 3072){
    int i = (bid*256 + threadIdx.x)*8;
    cvt8(x + i, xb + i);
  } else if (bid < 3456){
    int i = ((bid-3072)*256 + threadIdx.x)*8;
    cvt8(wq + i, wqb + i);
  } else {
    int idx = (bid-3456)*256 + threadIdx.x;
    float w0 = wconv[idx*3+0], w1 = wconv[idx*3+1], w2 = wconv[idx*3+2];
    wc3[idx]          = f2bf(w0);
    wc3[262144 + idx] = f2bf(w1);
    wc3[524288 + idx] = f2bf(w2);
  }
}

// ---------------- K1: QKV projection GEMM, m97-style 128x128 tile ----------------
__global__ __launch_bounds__(256) void k_qkv(const unsigned short* __restrict__ xb,
    const unsigned short* __restrict__ wq, const float* __restrict__ bias,
    unsigned short* __restrict__ qe, unsigned short* __restrict__ kb,
    unsigned short* __restrict__ vb){
  __shared__ unsigned short sA[128*32];
  __shared__ unsigned short sB[128*32];
  int bm = blockIdx.x % 96, bn = blockIdx.x / 96;
  int m0 = bm*128, n0 = bn*128;
  int tid = threadIdx.x, w = tid>>6, l = tid&63;
  int wr = w>>1, wc = w&1, lr = l&15, lk = (l>>4)*8;

  int srow = w*32 + (l>>2);
  int scol = (l&3)*8;
  const unsigned short* gA = xb + (size_t)(m0 + srow)*DM + scol;
  const unsigned short* gB = wq + (size_t)(n0 + srow)*DM + scol;
  unsigned short* dA = sA + w*1024;
  unsigned short* dB = sB + w*1024;

  const unsigned short* ra = sA + (wr*64 + lr)*32 + lk;
  const unsigned short* rb = sB + (wc*64 + lr)*32 + lk;

  f32x4 z = {0.f,0.f,0.f,0.f};
  f32x4 acc[4][4] = {{z,z,z,z},{z,z,z,z},{z,z,z,z},{z,z,z,z}};

  #pragma unroll 1
  for (int ks=0; ks<16; ++ks){
    int k0 = ks*32;
    gload16(gA + k0,          dA);
    gload16(gA + 16*DM + k0,  dA + 512);
    gload16(gB + k0,          dB);
    gload16(gB + 16*DM + k0,  dB + 512);
    __syncthreads();
    bf16x8 af[4], bfr[4];
    #pragma unroll
    for (int f=0; f<4; ++f){
      af[f]  = *reinterpret_cast<const bf16x8*>(ra + f*512);
      bfr[f] = *reinterpret_cast<const bf16x8*>(rb + f*512);
    }
    #pragma unroll
    for (int fq=0; fq<4; ++fq)
      #pragma unroll
      for (int fn=0; fn<4; ++fn)
        acc[fq][fn] = MFMA(af[fq], bfr[fn], acc[fq][fn]);
    __syncthreads();
  }

  int region = n0 >> 9;
  #pragma unroll
  for (int fq=0; fq<4; ++fq)
    #pragma unroll
    for (int fn=0; fn<4; ++fn)
      #pragma unroll
      for (int r=0; r<4; ++r){
        int m = m0 + wr*64 + fq*16 + (l>>4)*4 + r;
        int b = m / TSEQ, t = m - b*TSEQ;
        int n = n0 + wc*64 + fn*16 + lr;
        float val = acc[fq][fn][r] + bias[n];
        unsigned short bv = f2bf(val);
        int bh = b*NH + ((n>>6)&7); int d = n & 63;
        if (region == 0){ if((t&1)==0) qe[((size_t)bh*TOUT + (t>>1))*DKH + d] = bv; }
        else if (region == 1){ kb[((size_t)bh*TSEQ + t)*DKH + d] = bv; }
        else { vb[((size_t)bh*TSEQ + t)*DKH + d] = bv; }
      }
}

// ---------------- K1b: v transpose [bh][768][64] -> [bh][64][768] ----------------
__global__ __launch_bounds__(256) void k_vt(const unsigned short* __restrict__ vb,
                                            unsigned short* __restrict__ vT){
  __shared__ unsigned short tile[64][72];
  int bh = blockIdx.x / 12, tt = blockIdx.x % 12;
  int t0 = tt*64;
  int tid = threadIdx.x;
  int r = tid >> 2, c0 = (tid & 3) * 16;
  const unsigned short* src = vb + ((size_t)bh*TSEQ + t0 + r)*DKH + c0;
  *reinterpret_cast<bf16x8*>(&tile[r][c0])   = *reinterpret_cast<const bf16x8*>(src);
  *reinterpret_cast<bf16x8*>(&tile[r][c0+8]) = *reinterpret_cast<const bf16x8*>(src + 8);
  __syncthreads();
  int d = r;
  unsigned short tmp[16];
  #pragma unroll
  for (int j=0;j<16;++j) tmp[j] = tile[c0+j][d];
  unsigned short* dst = vT + ((size_t)bh*DKH + d)*TSEQ + t0 + c0;
  *reinterpret_cast<bf16x8*>(dst)     = *reinterpret_cast<bf16x8*>(tmp);
  *reinterpret_cast<bf16x8*>(dst + 8) = *reinterpret_cast<bf16x8*>(tmp + 8);
}

// ---------------- K2: scores MFMA + 2-row-packed f16 bitonic sort + softmax + PV MFMA ----------------
// Phase B is the r8/r10-proven version (152.8 us). r11's sign-flip restructure
// broke compile-time unrolling (runtime dl -> all exchanges via ds_bpermute,
// 287 us) and was reverted.
#define SQ_ROWB 3088   // bytes per fp32 score row (772 floats, 16B aligned)
__global__ __launch_bounds__(512, 4) void k_attn(const unsigned short* __restrict__ qe,
    const unsigned short* __restrict__ kb, const unsigned short* __restrict__ vT,
    float* __restrict__ attn){
  __shared__ alignas(16) char sq_raw[16*SQ_ROWB];   // 49408 B
  int bh = blockIdx.x / 24, qb = blockIdx.x % 24;
  int tid = threadIdx.x, w = tid>>6, l = tid&63, lr = l&15, lk = (l>>4)*8;

  // ---- phase A: scores C[16 q][768 k] = q[16][64] . kb[768][64]^T, scaled 1/8
  const unsigned short* qbase = qe + ((size_t)bh*TOUT + qb*16)*DKH;
  bf16x8 qa0 = *reinterpret_cast<const bf16x8*>(qbase + lr*DKH + lk);
  bf16x8 qa1 = *reinterpret_cast<const bf16x8*>(qbase + lr*DKH + 32 + lk);
  const unsigned short* kbase = kb + (size_t)bh*TSEQ*DKH;
  #pragma unroll
  for (int i=0;i<6;++i){
    int nt = w + 8*i;
    const unsigned short* kr = kbase + (size_t)(nt*16 + lr)*DKH + lk;
    bf16x8 B0 = *reinterpret_cast<const bf16x8*>(kr);
    bf16x8 B1 = *reinterpret_cast<const bf16x8*>(kr + 32);
    f32x4 c = {0.f,0.f,0.f,0.f};
    c = MFMA(qa0,B0,c);
    c = MFMA(qa1,B1,c);
    int col = nt*16 + lr;
    int A = col*4;
    int sw = A ^ (((A >> 8) & 7) << 4);   // XOR swizzle within row (16B slots)
    #pragma unroll
    for (int r=0;r<4;++r){
      int qr = (l>>4)*4 + r;
      *reinterpret_cast<float*>(sq_raw + qr*SQ_ROWB + sw) = c[r] * 0.125f;
    }
  }
  __syncthreads();

  // ---- phase B: one packed network pass sorts both of this wave's rows
  {
    char* rowA = sq_raw + (w*2)*SQ_ROWB;
    char* rowB = rowA + SQ_ROWB;
    unsigned wv[16];
    if (l < 48){
      #pragma unroll
      for (int i4=0;i4<4;++i4){
        int A = l*64 + i4*16;
        int Asw = A ^ (((A >> 8) & 7) << 4);
        f32x4 va = *reinterpret_cast<f32x4*>(rowA + Asw);
        f32x4 vb = *reinterpret_cast<f32x4*>(rowB + Asw);
        wv[i4*4+0] = pkrtz(va[0], vb[0]);
        wv[i4*4+1] = pkrtz(va[1], vb[1]);
        wv[i4*4+2] = pkrtz(va[2], vb[2]);
        wv[i4*4+3] = pkrtz(va[3], vb[3]);
      }
    } else {
      #pragma unroll
      for (int j=0;j<16;++j) wv[j] = 0xFC00FC00u;   // (-inf, -inf) f16
    }
    int lane16 = l << 4;   // e = 16*l + j
    #pragma unroll
    for (int k = 2; k <= 1024; k <<= 1){
      #pragma unroll
      for (int D = k>>1; D >= 16; D >>= 1){
        int dl = D >> 4;
        bool sel = ((lane16 & k) == 0) == ((l & dl) == 0);
        #pragma unroll
        for (int j=0;j<16;++j){
          unsigned y  = xlane_xor_u(wv[j], dl);
          unsigned mx = pmax2(wv[j], y), mn = pmin2(wv[j], y);
          wv[j] = sel ? mx : mn;
        }
      }
      #pragma unroll
      for (int D = ((k>>1) > 8 ? 8 : (k>>1)); D >= 1; D >>= 1){
        #pragma unroll
        for (int j=0;j<16;++j){
          if ((j & D) == 0){
            int j2 = j | D;
            unsigned mx = pmax2(wv[j], wv[j2]), mn = pmin2(wv[j], wv[j2]);
            if (k <= 8){
              if ((j & k) == 0){ wv[j] = mx; wv[j2] = mn; }
              else             { wv[j] = mn; wv[j2] = mx; }
            } else {
              bool up = (k == 16) ? ((l & 1) == 0) : ((lane16 & k) == 0);
              wv[j]  = up ? mx : mn;
              wv[j2] = up ? mn : mx;
            }
          }
        }
      }
    }
    // softmax per row (lo = row A, hi = row B)
    #pragma unroll 1
    for (int half=0; half<2; ++half){
      float xf[16];
      #pragma unroll
      for (int j=0;j<16;++j) xf[j] = half ? hi16f(wv[j]) : lo16f(wv[j]);
      float mx0 = __shfl(xf[0], 0, 64);
      float s = 0.f;
      #pragma unroll
      for (int j=0;j<16;++j){ xf[j] = __expf(xf[j]-mx0); s += xf[j]; }
      #pragma unroll
      for (int o=1;o<64;o<<=1) s += xlane_xor_f(s, o);
      float inv = 1.f / s;
      if (l < 48){
        unsigned short u[16];
        #pragma unroll
        for (int j=0;j<16;++j) u[j] = f2bf(xf[j]*inv);
        char* pp = (half ? rowB : rowA) + l*32;
        *reinterpret_cast<bf16x8*>(pp)      = *reinterpret_cast<bf16x8*>(u);
        *reinterpret_cast<bf16x8*>(pp + 16) = *reinterpret_cast<bf16x8*>(u + 8);
      }
    }
  }
  __syncthreads();

  // ---- phase C: PV. C[16 q][64 d] = P[16][768] . vT[64][768]^T. waves 0-3 only.
  if (w < 4){
    f32x4 o = {0.f,0.f,0.f,0.f};
    const unsigned short* vtb = vT + ((size_t)bh*DKH + w*16 + lr)*TSEQ + lk;
    const char* prow = sq_raw + lr*SQ_ROWB + (l>>4)*16;
    #pragma unroll
    for (int ks=0; ks<24; ++ks){
      bf16x8 a  = *reinterpret_cast<const bf16x8*>(prow + ks*64);
      bf16x8 bb = *reinterpret_cast<const bf16x8*>(vtb + ks*32);
      o = MFMA(a,bb,o);
    }
    int b = bh >> 3, h = bh & 7;
    float* ab = attn + ((size_t)b*TOUT + qb*16)*DM + h*DKH + w*16 + lr;
    #pragma unroll
    for (int r=0;r<4;++r){
      int qr = (l>>4)*4 + r;
      ab[(size_t)qr*DM] = o[r];
    }
  }
}

// ---------------- K3: conv as 3 accumulated GEMMs, m97-style 128x64 tile ----------------
__global__ __launch_bounds__(256) void k_conv(const unsigned short* __restrict__ xb,
    const unsigned short* __restrict__ wc, const float* __restrict__ bconv,
    float* __restrict__ res){
  __shared__ unsigned short sA[128*32];
  __shared__ unsigned short sB[64*32];
  int bm = blockIdx.x % 48, bn = blockIdx.x / 48;   // 48 x 8 blocks
  int m0 = bm*128, n0 = bn*64;
  int tid = threadIdx.x, w = tid>>6, l = tid&63;
  int wr = w>>1, wc2 = w&1, lr = l&15, lk = (l>>4)*8;
  int b = m0 / TOUT, t0 = m0 - b*TOUT;   // 384 = 3*128: tile never straddles batches

  int srowA = w*32 + (l>>2);       // A rows, 2 issues (second = +16)
  int srowB = w*16 + (l>>2);       // B rows, 1 issue
  int scol = (l&3)*8;
  const unsigned short* xrow = xb + (size_t)b*TSEQ*DM;
  unsigned short* dA = sA + w*1024;
  unsigned short* dB = sB + w*512;
  const unsigned short* ra  = sA + (wr*64 + lr)*32 + lk;
  const unsigned short* rb_ = sB + (wc2*32 + lr)*32 + lk;

  f32x4 z = {0.f,0.f,0.f,0.f};
  f32x4 acc[4][2] = {{z,z},{z,z},{z,z},{z,z}};
  bool zfix = (t0 == 0);

  #pragma unroll 1
  for (int j=0; j<3; ++j){
    int tin0 = 2*(t0 + srowA) + j - 1;
    int tin0c = tin0 < 0 ? 0 : tin0;
    const unsigned short* gA0 = xrow + (size_t)tin0c*DM + scol;
    const unsigned short* gA1 = xrow + (size_t)(tin0 + 32)*DM + scol;
    const unsigned short* gB  = wc + (size_t)j*262144 + (size_t)(n0 + srowB)*DM + scol;
    bool dz = zfix && (j == 0);
    #pragma unroll 1
    for (int ks=0; ks<16; ++ks){
      int k0 = ks*32;
      gload16(gA0 + k0, dA);
      gload16(gA1 + k0, dA + 512);
      gload16(gB + k0,  dB);
      __syncthreads();
      if (dz && tid < 4){
        bf16x8 zz = {0,0,0,0,0,0,0,0};
        *reinterpret_cast<bf16x8*>(sA + tid*8) = zz;   // zero A row 0 (pad)
      }
      __syncthreads();
      bf16x8 af[4], bfr[2];
      #pragma unroll
      for (int f=0; f<4; ++f) af[f] = *reinterpret_cast<const bf16x8*>(ra + f*512);
      #pragma unroll
      for (int f=0; f<2; ++f) bfr[f] = *reinterpret_cast<const bf16x8*>(rb_ + f*512);
      #pragma unroll
      for (int fq=0; fq<4; ++fq)
        #pragma unroll
        for (int fn=0; fn<2; ++fn)
          acc[fq][fn] = MFMA(af[fq], bfr[fn], acc[fq][fn]);
      __syncthreads();
    }
  }

  #pragma unroll
  for (int fq=0; fq<4; ++fq)
    #pragma unroll
    for (int fn=0; fn<2; ++fn)
      #pragma unroll
      for (int r=0; r<4; ++r){
        int t = t0 + wr*64 + fq*16 + (l>>4)*4 + r;
        int n = n0 + wc2*32 + fn*16 + lr;
        size_t idx = ((size_t)b*TOUT + t)*DM + n;
        res[idx] = acc[fq][fn][r] + bconv[n] + res[idx];
      }
}

// ---------------- K4: LayerNorm over D=512, one wave per row ----------------
__global__ __launch_bounds__(256) void k_ln(const float* __restrict__ res,
    const float* __restrict__ gamma, const float* __restrict__ beta,
    float* __restrict__ out){
  int row = blockIdx.x*4 + (threadIdx.x>>6);
  int l = threadIdx.x & 63;
  const float* rp = res + (size_t)row*DM + l*8;
  float4 v0 = *reinterpret_cast<const float4*>(rp);
  float4 v1 = *reinterpret_cast<const float4*>(rp + 4);
  float s = v0.x+v0.y+v0.z+v0.w + v1.x+v1.y+v1.z+v1.w;
  #pragma unroll
  for (int o=1;o<64;o<<=1) s += __shfl_xor(s, o, 64);
  float mean = s * (1.f/512.f);
  float d0=v0.x-mean, d1=v0.y-mean, d2=v0.z-mean, d3=v0.w-mean;
  float d4=v1.x-mean, d5=v1.y-mean, d6=v1.z-mean, d7=v1.w-mean;
  float q = d0*d0+d1*d1+d2*d2+d3*d3+d4*d4+d5*d5+d6*d6+d7*d7;
  #pragma unroll
  for (int o=1;o<64;o<<=1) q += __shfl_xor(q, o, 64);
  float var = q * (1.f/512.f);
  float inv = rsqrtf(var + 1e-5f);
  float4 g0 = *reinterpret_cast<const float4*>(gamma + l*8);
  float4 g1 = *reinterpret_cast<const float4*>(gamma + l*8 + 4);
  float4 b0 = *reinterpret_cast<const float4*>(beta + l*8);
  float4 b1 = *reinterpret_cast<const float4*>(beta + l*8 + 4);
  float4 o0, o1;
  o0.x = d0*inv*g0.x + b0.x; o0.y = d1*inv*g0.y + b0.y;
  o0.z = d2*inv*g0.z + b0.z; o0.w = d3*inv*g0.w + b0.w;
  o1.x = d4*inv*g1.x + b1.x; o1.y = d5*inv*g1.y + b1.y;
  o1.z = d6*inv*g1.z + b1.z; o1.w = d7*inv*g1.w + b1.w;
  float* op = out + (size_t)row*DM + l*8;
  *reinterpret_cast<float4*>(op)     = o0;
  *reinterpret_cast<float4*>(op + 4) = o1;
}

extern "C" void kernel_launch(void* const* d_in, const int* in_sizes, int n_in,
                              void* d_out, int out_size, void* d_ws, size_t ws_size,
                              hipStream_t stream){
  const float* x     = (const float*)d_in[0];
  const float* Wqkv  = (const float*)d_in[1];
  const float* bqkv  = (const float*)d_in[2];
  const float* Wconv = (const float*)d_in[3];
  const float* bconv = (const float*)d_in[4];
  const float* gamma = (const float*)d_in[5];
  const float* beta  = (const float*)d_in[6];
  float* out = (float*)d_out;

  char* ws = (char*)d_ws;
  size_t off = 0;
  auto alloc = [&](size_t bytes)->char*{
    char* p = ws + off; off += (bytes + 255) & ~(size_t)255; return p;
  };
  unsigned short* xb  = (unsigned short*)alloc(6291456ull*2);  // x bf16 [12288][512]
  unsigned short* wqb = (unsigned short*)alloc(786432ull*2);   // Wqkv bf16 [1536][512]
  unsigned short* wc3 = (unsigned short*)alloc(786432ull*2);   // Wconv repack [3][512][512]
  unsigned short* qeb = (unsigned short*)alloc(3145728ull*2);  // q even rows [128][384][64]
  unsigned short* kbb = (unsigned short*)alloc(6291456ull*2);  // k [128][768][64]
  unsigned short* vbb = (unsigned short*)alloc(6291456ull*2);  // v [128][768][64]
  unsigned short* vtb = (unsigned short*)alloc(6291456ull*2);  // v^T [128][64][768]
  float*          resb = (float*)alloc(3145728ull*4);          // attn(even) then +conv residual

  k_cvt_all<<<dim3(4480), dim3(256), 0, stream>>>(x, Wqkv, Wconv, xb, wqb, wc3);
  k_qkv<<<dim3(1152), dim3(256), 0, stream>>>(xb, wqb, bqkv, qeb, kbb, vbb);
  k_vt<<<dim3(1536), dim3(256), 0, stream>>>(vbb, vtb);
  k_attn<<<dim3(3072), dim3(512), 0, stream>>>(qeb, kbb, vtb, resb);
  k_conv<<<dim3(384), dim3(256), 0, stream>>>(xb, wc3, bconv, resb);
  k_ln<<<dim3(1536), dim3(256), 0, stream>>>(resb, gamma, beta, out);
}